// Round 22
// baseline (346.580 us; speedup 1.0000x reference)
//
#include <hip/hip_runtime.h>
#include <hip/hip_bf16.h>

// Problem constants
#define NB 8
#define NL 2500
#define ND 512
#define NY 8921

// Tiling
#define BM 256             // G rows per block (128 labels, U/W interleaved)
#define BN 256             // l-tile
#define BK 32              // k-slice (2 slices per K-tile of 64)
#define NKS 16             // slices per l-tile
#define LPAD 2560          // 10 * 256
#define NLT 10             // LPAD/BN
#define NYB 70             // ceil(NY/128)
#define YPAD 8960          // NYB*128

#define SPLIT 5            // l-range splits (2 l-tiles per block)
#define LSPL_MAIN 2

#define TILE 16384         // 256 rows x 32 bf16 (64B/row), row-pair swizzled image
#define GT_BYTES ((size_t)NYB * NKS * TILE)              // 18,350,080
#define XT_BYTES ((size_t)NB * NLT * NKS * TILE)         // 20,971,520
#define P_ELEMS  ((size_t)SPLIT * NB * YPAD)             // 358,400
#define P_BYTES  (P_ELEMS * 4)

#define GCVT_BLKS 4480     // G granules: 17920 rows * 64 / 256
#define XCVT_BLKS 5120     // X granules: 20480 rows * 64 / 256

typedef short s8v __attribute__((ext_vector_type(8)));
typedef float f4v __attribute__((ext_vector_type(4)));

__device__ __forceinline__ unsigned short f2bf(float f) {
  unsigned int u = __float_as_uint(f);
  return (unsigned short)((u + 0x7FFFu + ((u >> 16) & 1u)) >> 16);
}
__device__ __forceinline__ unsigned int pk2(float a, float b) {
  return (unsigned int)f2bf(a) | ((unsigned int)f2bf(b) << 16);
}
__device__ __forceinline__ void async_copy16(const char* g, char* l) {
  __builtin_amdgcn_global_load_lds(
      (const __attribute__((address_space(1))) void*)g,
      (__attribute__((address_space(3))) void*)l, 16, 0, 0);
}

// Swizzled tile byte offset for (row r in [0,256), 16B-granule gn in [0,4)):
// row-pair rp=r>>1 owns a 128B line; within-line = ((r&1)*64 + gn*16) ^ ((rp&7)<<4)
__device__ __forceinline__ int tile_off(int r, int gn) {
  int rp = r >> 1;
  return rp * 128 + ((((r & 1) << 6) | (gn << 4)) ^ ((rp & 7) << 4));
}

// ---- merged conversion: one launch does both G and X images (co-fills GPU)
__global__ void cvt_all_kernel(const float* __restrict__ U, const float* __restrict__ W,
                               const float* __restrict__ x,
                               char* __restrict__ Gt, char* __restrict__ Xt) {
  if (blockIdx.x < GCVT_BLKS) {
    int c = blockIdx.x * 256 + threadIdx.x;    // one 16B granule
    int g10 = c & 1023;
    int tile = c >> 10;                        // yblk*16 + ks
    int ks = tile & 15, yblk = tile >> 4;
    int r = g10 >> 2, gn = g10 & 3;
    int rg = yblk * 256 + r;
    int y = rg >> 1;
    uint4 o;
    if (y < NY) {
      const float* src = (rg & 1) ? W : U;
      const float4* p = (const float4*)(src + (size_t)y * ND + ks * BK + gn * 8);
      float4 f0 = p[0], f1 = p[1];
      o.x = pk2(f0.x, f0.y); o.y = pk2(f0.z, f0.w);
      o.z = pk2(f1.x, f1.y); o.w = pk2(f1.z, f1.w);
    } else {
      o = make_uint4(0u, 0u, 0u, 0u);
    }
    *(uint4*)(Gt + (size_t)tile * TILE + tile_off(r, gn)) = o;
  } else {
    int c = (blockIdx.x - GCVT_BLKS) * 256 + threadIdx.x;
    int g10 = c & 1023;
    int tile = c >> 10;                        // (b*10+t)*16 + ks
    int ks = tile & 15, rest = tile >> 4;
    int t = rest % NLT, b = rest / NLT;
    int r = g10 >> 2, gn = g10 & 3;
    int l = t * 256 + r;
    uint4 o;
    if (l < NL) {
      const float4* p = (const float4*)(x + ((size_t)b * NL + l) * ND + ks * BK + gn * 8);
      float4 f0 = p[0], f1 = p[1];
      o.x = pk2(f0.x, f0.y); o.y = pk2(f0.z, f0.w);
      o.z = pk2(f1.x, f1.y); o.w = pk2(f1.z, f1.w);
    } else {
      o = make_uint4(0u, 0u, 0u, 0u);
    }
    *(uint4*)(Xt + (size_t)tile * TILE + tile_off(r, gn)) = o;
  }
}

// ---- fused dual-GEMM + deferred softmax; 512 thr = 8 waves (2M x 4N), 256x256 tile
// m201 schedule, 2 barriers/K-tile (the minimum correct set): ONLY the two
// VMC(2)+publish barriers remain (ph0: odd half of THIS tile; ph2: even half of
// NEXT tile). All pacing-only barriers removed across r20/r21/this round —
// hazard-audited: every LDS read is covered by a publish barrier already crossed,
// every stage-write targets a region whose readers retired (wave-local lgkm)
// before >=2 intervening barriers. lgkm/vm ledgers are wave-local and unchanged.
template<int LSPL, int NSPL, bool PARTIAL>
__global__ __launch_bounds__(512, 2) void fused_kernel(
    const char* __restrict__ Gt, const char* __restrict__ Xt,
    const float* __restrict__ bias, float* __restrict__ out,
    float* __restrict__ PD, float* __restrict__ PN)
{
  __shared__ uint4 ring[8192];         // 128 KB: A bufs [0,64K), B bufs [64K,128K)
  char* ringC = (char*)ring;

  constexpr int NKT = LSPL * 8;        // K-tiles (BK=64) per block

  const int tid  = threadIdx.x;
  const int lane = tid & 63;
  const int w    = tid >> 6;           // 0..7
  const int wr   = w >> 2;             // 0..1  M-half (128 G-rows)
  const int wc   = w & 3;              // 0..3  N-quarter (64 l)
  const int cl   = lane & 15, g = lane >> 4;

  const int id    = blockIdx.x;
  const int bb    = id & 7;            // batch, XCD-pinned
  const int n     = id >> 3;
  const int yblk  = n / NSPL;
  const int split = n - yblk * NSPL;
  const int tbase = split * LSPL;

  const char* GA = Gt + (size_t)yblk * NKS * TILE;
  const char* XB = Xt + ((size_t)bb * NLT + tbase) * NKS * TILE;

  f4v acc[8][4];
  float runD[8][2], runN[8][2];
  #pragma unroll
  for (int mi = 0; mi < 8; ++mi)
    #pragma unroll
    for (int p = 0; p < 2; ++p) { runD[mi][p] = 0.f; runN[mi][p] = 0.f; }

  int aoff[8], boff[4];
  #pragma unroll
  for (int j = 0; j < 8; ++j) aoff[j] = tile_off(wr * 128 + j * 16 + cl, g);
  #pragma unroll
  for (int ni = 0; ni < 4; ++ni) boff[ni] = tile_off(wc * 64 + ni * 16 + cl, g);

  const int t16 = tid << 4;
  auto stgA = [&](int kt1, int par) {  // 2 vm-events/wave: A slice -> buf kt1&1
    const char* ga = GA + (size_t)((((kt1 & 7) << 1) | par)) * TILE;
    char* la = ringC + (kt1 & 1) * 32768 + par * 16384 + (w << 10);
    async_copy16(ga + t16, la);
    async_copy16(ga + 8192 + t16, la + 8192);
  };
  auto stgB = [&](int kt1, int par) {
    const char* gb = XB + (size_t)((kt1 >> 3) * 16 + ((kt1 & 7) << 1) + par) * TILE;
    char* lb = ringC + 65536 + (kt1 & 1) * 32768 + par * 16384 + (w << 10);
    async_copy16(gb + t16, lb);
    async_copy16(gb + 8192 + t16, lb + 8192);
  };

  auto softmax_acc = [&](int tt) {     // deferred: per-lane sums, no shuffles
    const int lbase = (tbase + tt) * BN + wc * 64 + cl;
    #pragma unroll
    for (int mi = 0; mi < 8; ++mi) {
      #pragma unroll
      for (int p = 0; p < 2; ++p) {
        float se = 0.f, ste = 0.f;
        #pragma unroll
        for (int ni = 0; ni < 4; ++ni) {
          bool valid = (lbase + ni * 16) < NL;
          float sv = valid ? acc[mi][ni][2 * p] : -1e30f;
          float e = __expf(sv);
          se += e;
          ste += e * acc[mi][ni][2 * p + 1];
        }
        runD[mi][p] += se;
        runN[mi][p] += ste;
      }
    }
  };

#define SBAR __builtin_amdgcn_sched_barrier(0)
#define LGKM(N) asm volatile("s_waitcnt lgkmcnt(" #N ")" ::: "memory")
#define VMC(N)  asm volatile("s_waitcnt vmcnt(" #N ")" ::: "memory")

  // prologue: stage K-tile 0 fully (8 events); retire even half (vmcnt 4); publish
  stgA(0, 0); stgB(0, 0); stgA(0, 1); stgB(0, 1);
  VMC(4);
  __builtin_amdgcn_s_barrier();
  asm volatile("" ::: "memory");

  // frag registers (named sets, static indexing)
  s8v bvE[4], bvO[4], afX[4], afY[4];
  // primer: Q0 reads of kt=0 (even slice, buf 0)
  #pragma unroll
  for (int ni = 0; ni < 4; ++ni) bvE[ni] = *(const s8v*)(ringC + 65536 + boff[ni]);
  #pragma unroll
  for (int j = 0; j < 4; ++j)    afX[j] = *(const s8v*)(ringC + aoff[j]);

  for (int kt = 0; kt < NKT; ++kt) {
    const int buf = kt & 1;
    const char* Ae = ringC + buf * 32768;
    const char* Ao = Ae + 16384;
    const char* Bo = ringC + 65536 + buf * 32768 + 16384;
    const char* Aen = ringC + (buf ^ 1) * 32768;
    const char* Ben = ringC + 65536 + (buf ^ 1) * 32768;
    const bool hn = (kt + 1) < NKT;

    if ((kt & 7) == 0) {
      if (kt > 0) softmax_acc((kt >> 3) - 1);
      #pragma unroll
      for (int mi = 0; mi < 8; ++mi)
        #pragma unroll
        for (int ni = 0; ni < 4; ++ni)
          #pragma unroll
          for (int q = 0; q < 4; ++q) acc[mi][ni][q] = 0.f;
    }

    // ---- ph0: stage As0' | read afY(even hi) -> MFMA Q0 (afX,bvE) -> VMC -> bar
    if (hn) stgA(kt + 1, 0);
    #pragma unroll
    for (int j = 0; j < 4; ++j) afY[j] = *(const s8v*)(Ae + aoff[4 + j]);
    SBAR;
    LGKM(4); SBAR;
    __builtin_amdgcn_s_setprio(1);
    #pragma unroll
    for (int j = 0; j < 4; ++j)
      #pragma unroll
      for (int ni = 0; ni < 4; ++ni)
        acc[j][ni] = __builtin_amdgcn_mfma_f32_16x16x32_bf16(afX[j], bvE[ni], acc[j][ni], 0, 0, 0);
    __builtin_amdgcn_s_setprio(0);
    if (hn) { VMC(2); } else { VMC(0); }   // publish odd half of THIS K-tile
    SBAR;
    __builtin_amdgcn_s_barrier();
    asm volatile("" ::: "memory");

    // ---- ph1: stage Bs0' | read bvO+afX(odd lo) -> MFMA Q1 (afY,bvE)  [no barriers]
    if (hn) stgB(kt + 1, 0);
    #pragma unroll
    for (int ni = 0; ni < 4; ++ni) bvO[ni] = *(const s8v*)(Bo + boff[ni]);
    #pragma unroll
    for (int j = 0; j < 4; ++j)    afX[j] = *(const s8v*)(Ao + aoff[j]);
    SBAR;
    LGKM(8); SBAR;
    __builtin_amdgcn_s_setprio(1);
    #pragma unroll
    for (int j = 0; j < 4; ++j)
      #pragma unroll
      for (int ni = 0; ni < 4; ++ni)
        acc[4 + j][ni] = __builtin_amdgcn_mfma_f32_16x16x32_bf16(afY[j], bvE[ni], acc[4 + j][ni], 0, 0, 0);
    __builtin_amdgcn_s_setprio(0);

    // ---- ph2: stage As1' | read afY(odd hi) -> MFMA Q2 (afX,bvO) -> VMC -> bar
    if (hn) stgA(kt + 1, 1);
    #pragma unroll
    for (int j = 0; j < 4; ++j) afY[j] = *(const s8v*)(Ao + aoff[4 + j]);
    SBAR;
    LGKM(4); SBAR;
    __builtin_amdgcn_s_setprio(1);
    #pragma unroll
    for (int j = 0; j < 4; ++j)
      #pragma unroll
      for (int ni = 0; ni < 4; ++ni)
        acc[j][ni] = __builtin_amdgcn_mfma_f32_16x16x32_bf16(afX[j], bvO[ni], acc[j][ni], 0, 0, 0);
    __builtin_amdgcn_s_setprio(0);
    if (hn) VMC(2);                        // publish even half of NEXT K-tile
    SBAR;
    __builtin_amdgcn_s_barrier();
    asm volatile("" ::: "memory");

    // ---- ph3: stage Bs1' | read bvE'+afX'(next even lo) -> MFMA Q3 (afY,bvO)  [no barriers]
    if (hn) {
      stgB(kt + 1, 1);
      #pragma unroll
      for (int ni = 0; ni < 4; ++ni) bvE[ni] = *(const s8v*)(Ben + boff[ni]);
      #pragma unroll
      for (int j = 0; j < 4; ++j)    afX[j] = *(const s8v*)(Aen + aoff[j]);
      SBAR;
      LGKM(8); SBAR;
    } else {
      SBAR;
      LGKM(0); SBAR;
    }
    __builtin_amdgcn_s_setprio(1);
    #pragma unroll
    for (int j = 0; j < 4; ++j)
      #pragma unroll
      for (int ni = 0; ni < 4; ++ni)
        acc[4 + j][ni] = __builtin_amdgcn_mfma_f32_16x16x32_bf16(afY[j], bvO[ni], acc[4 + j][ni], 0, 0, 0);
    __builtin_amdgcn_s_setprio(0);
  }
  softmax_acc(LSPL - 1);

#undef SBAR
#undef LGKM
#undef VMC

  // ---- once-per-kernel: 16-lane reduce of partials (plain sums)
  #pragma unroll
  for (int mi = 0; mi < 8; ++mi)
    #pragma unroll
    for (int p = 0; p < 2; ++p) {
      float d = runD[mi][p], nn = runN[mi][p];
      #pragma unroll
      for (int off = 1; off < 16; off <<= 1) {
        d += __shfl_xor(d, off);
        nn += __shfl_xor(nn, off);
      }
      runD[mi][p] = d; runN[mi][p] = nn;
    }

  // ---- 4-way wc merge via LDS (plain sums), then write partials / output
  __syncthreads();
  float* sm = (float*)ring;      // 128 labels x 4 wc x 2 floats = 4 KB
  if (cl == 0) {
    #pragma unroll
    for (int mi = 0; mi < 8; ++mi)
      #pragma unroll
      for (int p = 0; p < 2; ++p) {
        int lab = wr * 64 + mi * 8 + 2 * g + p;   // 0..127
        float* s2 = sm + (lab * 4 + wc) * 2;
        s2[0] = runD[mi][p]; s2[1] = runN[mi][p];
      }
  }
  __syncthreads();
  if (tid < 128) {
    float D = 0.f, N = 0.f;
    #pragma unroll
    for (int q = 0; q < 4; ++q) {
      const float* s2 = sm + (tid * 4 + q) * 2;
      D += s2[0]; N += s2[1];
    }
    int y = yblk * 128 + tid;
    if constexpr (PARTIAL) {
      size_t o = ((size_t)split * NB + bb) * YPAD + y;
      PD[o] = D; PN[o] = N;
    } else {
      if (y < NY) out[(size_t)bb * NY + y] = N / D + bias[y];
    }
  }
}

// ---- merge SPLIT partials + bias -> out (plain sums)
__global__ void merge_kernel(const float* __restrict__ PD, const float* __restrict__ PN,
                             const float* __restrict__ bias, float* __restrict__ out) {
  int idx = blockIdx.x * 256 + threadIdx.x;      // NB*YPAD
  int b = idx / YPAD, y = idx - b * YPAD;
  if (y >= NY) return;
  float D = 0.f, N = 0.f;
  #pragma unroll
  for (int s = 0; s < SPLIT; ++s) {
    size_t o = ((size_t)s * NB + b) * YPAD + y;
    D += PD[o];
    N += PN[o];
  }
  out[(size_t)b * NY + y] = N / D + bias[y];
}

extern "C" void kernel_launch(void* const* d_in, const int* in_sizes, int n_in,
                              void* d_out, int out_size, void* d_ws, size_t ws_size,
                              hipStream_t stream) {
  const float* xf   = (const float*)d_in[0];
  const float* Uf   = (const float*)d_in[1];
  const float* Wf   = (const float*)d_in[2];
  const float* bias = (const float*)d_in[3];
  float* out = (float*)d_out;

  char* Gt = (char*)d_ws;
  char* Xt = Gt + GT_BYTES;
  float* PD = (float*)(Xt + XT_BYTES);
  float* PN = PD + P_ELEMS;

  // merged conversion: G blocks [0,4480) + X blocks [4480,9600), one launch
  cvt_all_kernel<<<GCVT_BLKS + XCVT_BLKS, 256, 0, stream>>>(Uf, Wf, xf, Gt, Xt);

  const size_t need_main = GT_BYTES + XT_BYTES + 2 * P_BYTES;   // ~42.2 MB
  if (ws_size >= need_main) {
    fused_kernel<LSPL_MAIN, SPLIT, true><<<NYB * NB * SPLIT, 512, 0, stream>>>(
        Gt, Xt, bias, out, PD, PN);
    merge_kernel<<<NB * YPAD / 256, 256, 0, stream>>>(PD, PN, bias, out);
  } else {
    fused_kernel<NLT, 1, false><<<NYB * NB, 512, 0, stream>>>(
        Gt, Xt, bias, out, PD, PN);
  }
}